// Round 7
// baseline (123.771 us; speedup 1.0000x reference)
//
#include <hip/hip_runtime.h>

#define R_RAYS 16384
#define Z_ALL 192
#define WEPS 1e-5f
#define RPW 16          // rays per wave
#define NBLK 2048       // 2048 blocks x 4 waves x 16 rays = 131072 rays

typedef float f32x4 __attribute__((ext_vector_type(4)));

__device__ __forceinline__ float uval(int j) {
    return (j == 127) ? 1.0f : (float)j * (1.0f / 127.0f);
}

struct RayIn { float w, zv, ox, oy, oz, dx, dy, dz; };

__device__ __forceinline__ void load_ray(RayIn& in,
    const float* __restrict__ rays_d, const float* __restrict__ rays_o,
    const float* __restrict__ z_vals, const float* __restrict__ weights,
    int ray, int lane)
{
    in.w  = (lane < 62) ? weights[(size_t)ray * 64 + (lane + 1)] : 0.0f;
    in.zv = z_vals[(ray & (R_RAYS - 1)) * 64 + lane];
    in.ox = rays_o[ray * 3 + 0]; in.oy = rays_o[ray * 3 + 1]; in.oz = rays_o[ray * 3 + 2];
    in.dx = rays_d[ray * 3 + 0]; in.dy = rays_d[ray * 3 + 1]; in.dz = rays_d[ray * 3 + 2];
}

__global__ __launch_bounds__(256, 8) void ray_sampler_kernel(
    const float* __restrict__ rays_d,
    const float* __restrict__ rays_o,
    const float* __restrict__ z_vals,
    const float* __restrict__ weights,
    float* __restrict__ pts_out,
    float* __restrict__ zall_out)
{
    __shared__ __align__(16) float s_za[4][Z_ALL];   // wave-private slices

    const int wid  = threadIdx.x >> 6;
    const int lane = threadIdx.x & 63;
    int ray = (blockIdx.x * 4 + wid) * RPW;

    RayIn cur;
    load_ray(cur, rays_d, rays_o, z_vals, weights, ray, lane);

    #pragma unroll 1
    for (int i = 0; i < RPW; ++i) {
        // ---- prefetch next ray's inputs (hides HBM latency under compute) ----
        RayIn nxt = cur;
        if (i + 1 < RPW)
            load_ray(nxt, rays_d, rays_o, z_vals, weights, ray + 1, lane);

        // ---- per-lane register state: zv_l, zv_{l+1}, zh_l, zh_{l+1} ----
        float zv  = cur.zv;
        float zv1 = __shfl_down(zv, 1);
        float zv2 = __shfl_down(zv, 2);
        float zh  = 0.5f * (zv + zv1);        // bins[l]   (valid l<=62)
        float zh1 = 0.5f * (zv1 + zv2);       // bins[l+1] (valid l<=61)

        // ---- weights scan -> cdf interval [clo, chi) per lane ----
        float w = (lane < 62) ? cur.w + WEPS : 0.0f;
        float sc = w;
        #pragma unroll
        for (int off = 1; off < 64; off <<= 1) {
            float y = __shfl_up(sc, off);
            if (lane >= off) sc += y;
        }
        float total = __shfl(sc, 61);
        float scp   = __shfl_up(sc, 1);
        float clo = (lane == 0) ? 0.0f : scp / total;   // cdf[l]
        float chi = sc / total;                          // cdf[l+1]
        float denom = chi - clo;
        float rden  = (denom < 1e-5f) ? 1.0f : 1.0f / denom;
        float bhi = (lane >= 62) ? zh : zh1;

        // ---- ownership: js = min j with u_j >= clo ----
        int js = (int)ceilf(clo * 127.0f);
        js = js < 0 ? 0 : (js > 128 ? 128 : js);
        while (js > 0 && uval(js - 1) >= clo) --js;
        while (js < 128 && uval(js) < clo) ++js;
        int jn = __shfl_down(js, 1);
        int je = (lane == 62) ? 128 : ((lane > 62) ? js : jn);

        // ---- emit owned samples directly at final merged rank ----
        int cnt_lt = 0;
        for (int j = js; j < je; ++j) {
            float u = uval(j);
            float t = (u - clo) * rden;
            float s = fmaf(t, bhi - zh, zh);
            int ind = (zv1 <= s) ? 1 : 0;
            cnt_lt += 1 - ind;
            s_za[wid][j + lane + 1 + ind] = s;
        }
        if (lane == 0) s_za[wid][0] = zv;
        if (lane <= 62) s_za[wid][lane + 1 + js + cnt_lt] = zv1;

        // ---- per-wave vectorized drain (no barrier) ----
        const float* za = s_za[wid];
        const size_t pbase = (size_t)ray * (Z_ALL * 3);
        const size_t zbase = (size_t)ray * Z_ALL;
        #pragma unroll
        for (int t = 0; t < 3; ++t) {
            int idx = lane + 64 * t;                  // 0..191
            if (idx < 144) {
                int f0 = idx * 4;                     // 0..572
                int s0 = f0 / 3;
                float z0 = za[s0];
                float z1 = za[s0 + 1];
                f32x4 v;
                #pragma unroll
                for (int q = 0; q < 4; ++q) {
                    int gi = f0 + q;
                    int s  = gi / 3;
                    int c  = gi - s * 3;
                    float z = (s == s0) ? z0 : z1;
                    float o = (c == 0) ? cur.ox : ((c == 1) ? cur.oy : cur.oz);
                    float d = (c == 0) ? cur.dx : ((c == 1) ? cur.dy : cur.dz);
                    v[q] = fmaf(d, z, o);
                }
                __builtin_nontemporal_store(v, (f32x4*)(pts_out + pbase + f0));
            } else {
                int j = idx - 144;                    // 0..47
                f32x4 v = *(const f32x4*)&za[j * 4];
                __builtin_nontemporal_store(v, (f32x4*)(zall_out + zbase + j * 4));
            }
        }

        cur = nxt;
        ++ray;
    }
}

extern "C" void kernel_launch(void* const* d_in, const int* in_sizes, int n_in,
                              void* d_out, int out_size, void* d_ws, size_t ws_size,
                              hipStream_t stream) {
    const float* rays_d  = (const float*)d_in[0];
    const float* rays_o  = (const float*)d_in[1];
    const float* z_vals  = (const float*)d_in[2];
    const float* weights = (const float*)d_in[3];

    float* pts  = (float*)d_out;                       // (8,16384,192,3)
    float* zall = pts + (size_t)8 * 16384 * 192 * 3;   // (8,16384,192)

    dim3 grid(NBLK), block(256);
    ray_sampler_kernel<<<grid, block, 0, stream>>>(rays_d, rays_o, z_vals,
                                                   weights, pts, zall);
}